// Round 9
// baseline (163.304 us; speedup 1.0000x reference)
//
#include <hip/hip_runtime.h>
#include <hip/hip_bf16.h>
#include <math.h>

// Problem constants
#define NB 131072
#define NC 128
#define NE 128
__device__ constexpr float S_    = 100.0f;
__device__ constexpr float COSM_ = 0.5403023058681398f;   // cos(1)
__device__ constexpr float SINM_ = 0.8414709848078965f;   // sin(1)
__device__ constexpr float TH_   = -0.5403023058681398f;  // cos(pi-1)
__device__ constexpr float MM_   = 0.8414709848078965f;   // sin(pi-1)*1
__device__ constexpr float C0_   = 25.0f;                 // fixed logsumexp stabilizer

using short8 = __attribute__((ext_vector_type(8))) short;
using f32x4  = __attribute__((ext_vector_type(4))) float;

// packed fp32x2 -> bf16x2 (v_cvt_pk_bf16_f32)
__device__ __forceinline__ unsigned int pk2(float a, float b) {
    __hip_bfloat162 h = __float22bfloat162_rn(make_float2(a, b));
    union { __hip_bfloat162 h; unsigned int u; } cv; cv.h = h; return cv.u;
}
// fp32 -> bf16 (RNE) on raw bits (kernel 1)
__device__ __forceinline__ unsigned int bf1(float f) {
    unsigned int u = __float_as_uint(f);
    return (u + 0x7FFFu + ((u >> 16) & 1u)) >> 16;
}

// Kernel 1: normalize weight rows -> bf16 packed in ws; zero d_out.
__global__ void wnorm_kernel(const float* __restrict__ w,
                             unsigned int* __restrict__ wn,
                             float* __restrict__ out) {
    const int row = blockIdx.x;      // 128 rows
    const int lane = threadIdx.x;    // 64 lanes
    float2 v = ((const float2*)w)[row * 64 + lane];
    float ss = v.x * v.x + v.y * v.y;
    #pragma unroll
    for (int m = 1; m < 64; m <<= 1) ss += __shfl_xor(ss, m, 64);
    float sc = 1.0f / fmaxf(sqrtf(ss), 1e-12f);
    wn[row * 64 + lane] = bf1(v.x * sc) | (bf1(v.y * sc) << 16);
    if (row == 0 && lane == 0) *out = 0.0f;
}

// Kernel 1b (R11-proven): labels from one-hot target, CONTIGUOUS reads.
// Per j, 64 lanes read 1 KB (rows 2j,2j+1); iota-dot; 5-level shfl reduce
// within each 32-lane half; lanes 0/32 store the label byte.
// Streams 64 MB at ~5.3 TB/s (1024 one-shot blocks = natural overlap).
__global__ __launch_bounds__(256)
void label_kernel(const float* __restrict__ target,
                  unsigned char* __restrict__ labs) {
    const int t = threadIdx.x, lane = t & 63, wv = t >> 6;
    const long wbase = ((long)blockIdx.x * 4 + wv) * 32;   // this wave's 32 rows
    const char* src = (const char*)target + wbase * 512;
    const int l31 = lane & 31, half = lane >> 5;
    const float c0 = (float)(l31 * 4);
    #pragma unroll
    for (int j = 0; j < 16; ++j) {
        float4 v = *(const float4*)(src + j * 1024 + lane * 16);
        float p = fmaf(v.x, c0, fmaf(v.y, c0 + 1.f,
                  fmaf(v.z, c0 + 2.f, v.w * (c0 + 3.f))));
        p += __shfl_xor(p, 1, 64);
        p += __shfl_xor(p, 2, 64);
        p += __shfl_xor(p, 4, 64);
        p += __shfl_xor(p, 8, 64);
        p += __shfl_xor(p, 16, 64);
        if (l31 == 0) labs[wbase + 2 * j + half] = (unsigned char)(int)(p + 0.5f);
    }
}

constexpr int PITCH = 136;  // ushorts per LDS row for wn (272 B) — proven pattern

// global -> LDS DMA, 16 B per lane, fire-and-forget (counted by vmcnt).
__device__ __forceinline__ void gl2lds16(const void* g, void* l) {
    __builtin_amdgcn_global_load_lds(
        (const __attribute__((address_space(1))) void*)g,
        (__attribute__((address_space(3))) void*)l, 16, 0, 0);
}

// Stage one wave's 16-row predict slab (8 KB) into its private LDS buffer.
// 1 KB contiguous per instruction (rows 2j,2j+1); source carries the inverse
// XOR swizzle so the linear DMA dest lands pre-swizzled (rule #21).
__device__ __forceinline__ void stage_tile(const float* __restrict__ predict,
                                           long rowBase, float* lbase, int lane) {
    const char* g0 = (const char*)predict + rowBase * 512;
    const int rl_half = lane >> 5;
    const unsigned c = (unsigned)((lane & 31) * 16);
    #pragma unroll
    for (int j = 0; j < 8; ++j) {
        const int row_local = 2 * j + rl_half;
        const char* g = g0 + row_local * 512 + (c ^ ((unsigned)(row_local & 7) << 4));
        gl2lds16(g, (char*)lbase + j * 1024);
    }
}

// Read MFMA A-fragments (fp32, swizzled) from the wave's LDS slab,
// convert to bf16 + sumsq -> 1/||row|| (norm deferred to epilogue).
__device__ __forceinline__ float convert_lds(const float* pw, int l15, int quad,
                                             short8* af) {
    const char* base = (const char*)pw + l15 * 512;
    const unsigned swz = (unsigned)((l15 & 7) << 4);
    float s0 = 0.f;
    #pragma unroll
    for (int kc = 0; kc < 4; ++kc) {
        const unsigned b = (unsigned)(kc * 128 + quad * 32);
        float4 p0 = *(const float4*)(base + ((b) ^ swz));
        float4 p1 = *(const float4*)(base + ((b + 16) ^ swz));
        s0 += p0.x * p0.x + p0.y * p0.y + p0.z * p0.z + p0.w * p0.w;
        s0 += p1.x * p1.x + p1.y * p1.y + p1.z * p1.z + p1.w * p1.w;
        union { short8 s8; unsigned int u[4]; } uu;
        uu.u[0] = pk2(p0.x, p0.y);
        uu.u[1] = pk2(p0.z, p0.w);
        uu.u[2] = pk2(p1.x, p1.y);
        uu.u[3] = pk2(p1.z, p1.w);
        af[kc] = uu.s8;
    }
    s0 += __shfl_xor(s0, 16, 64);
    s0 += __shfl_xor(s0, 32, 64);
    return 1.0f / fmaxf(sqrtf(s0), 1e-12f);
}

__device__ __forceinline__ void mfma_tile(const unsigned short* sw, const short8* af,
                                          int l15, int quad, f32x4* acc) {
    #pragma unroll
    for (int tc = 0; tc < 8; ++tc) acc[tc] = (f32x4){0.f, 0.f, 0.f, 0.f};
    #pragma unroll 2
    for (int tc = 0; tc < 8; ++tc) {
        short8 b[4];
        #pragma unroll
        for (int kc = 0; kc < 4; ++kc)
            b[kc] = *(const short8*)(sw + (tc * 16 + l15) * PITCH + kc * 32 + quad * 8);
        #pragma unroll
        for (int kc = 0; kc < 4; ++kc)
            acc[tc] = __builtin_amdgcn_mfma_f32_16x16x32_bf16(af[kc], b[kc], acc[tc], 0, 0, 0);
    }
}

// arc-margin + per-row logsumexp contribution (R6-proven lean form)
__device__ __forceinline__ void epilogue(const f32x4* acc, int lab_all, float sc,
                                         int quad, int l15, float& lsum) {
    float se[4];
    #pragma unroll
    for (int v = 0; v < 4; ++v) {
        const int rl  = quad * 4 + v;
        const int lab = __shfl(lab_all, rl, 64);
        const float scv = __shfl(sc, rl, 64);
        const bool own  = (l15 == (lab & 15));
        const int  tcl  = lab >> 4;
        const float k1  = S_ * scv;
        float s = 1e-38f, craw = 0.f;
        #pragma unroll
        for (int tc = 0; tc < 8; ++tc) {
            float av = acc[tc][v];
            const bool isl = own && (tc == tcl);
            s += isl ? 0.f : __expf(fmaf(k1, av, -C0_));
            craw = isl ? av : craw;
        }
        float cl = craw * scv;
        float s2 = fmaxf(1.0f - cl * cl, 0.0f);
        float ph = cl * COSM_ - sqrtf(s2) * SINM_;
        ph = (cl > TH_) ? ph : (cl - MM_);
        s += own ? __expf(fmaf(S_, ph, -C0_)) : 0.f;
        lsum -= own ? S_ * ph : 0.f;
        se[v] = s;
    }
    #pragma unroll
    for (int m = 1; m < 16; m <<= 1) {
        #pragma unroll
        for (int v = 0; v < 4; ++v) se[v] += __shfl_xor(se[v], m, 64);
    }
    if (l15 == 0) {
        #pragma unroll
        for (int v = 0; v < 4; ++v) lsum += __logf(se[v]) + C0_;
    }
}

// Kernel 2: fused cosine GEMM + arc-margin + NLL.
// R14: ONE-SHOT blocks (2048 x 256 threads, 64 rows each) + contiguous DMA
// staging. The label kernel proved the overlap mechanism: one-shot blocks at
// 2 resident/CU x 8 generations overlap one block's DMA burst with another's
// compute — scheduler-managed, compiler-proof (R9/R10/R13 showed in-wave
// pipelining always gets collapsed). No software pipeline, 2 barriers total.
__global__ __launch_bounds__(256, 2)
void arcloss_kernel(const float* __restrict__ predict,
                    const unsigned char* __restrict__ labs,
                    const unsigned short* __restrict__ wns,
                    float* __restrict__ out) {
    __shared__ __align__(16) unsigned short sw[128 * PITCH];  // 34816 B
    __shared__ __align__(16) float pbuf[4 * 2048];            // 4 waves x 8 KB
    __shared__ float swsum[4];

    const int t    = threadIdx.x;
    const int lane = t & 63;
    const int wv   = t >> 6;         // 0..3
    const int l15  = lane & 15;
    const int quad = lane >> 4;
    const long rowBase = (long)blockIdx.x * 64 + wv * 16;  // this wave's 16 rows
    float* pw = pbuf + wv * 2048;    // this wave's private slab

    // ---- (1) predict DMA first: flies under wn/label loads + other block's compute ----
    stage_tile(predict, rowBase, pw, lane);

    // ---- (2) label byte (lane L needs row L&15's label) + wn loads ----
    const int labv = labs[rowBase + l15];
    const int srow = t >> 1, shalf = t & 1;   // 2 threads/row, 8 uint4 each
    uint4 wbuf[8];
    {
        const uint4* wsrc = (const uint4*)(wns + srow * 128 + shalf * 64);
        #pragma unroll
        for (int j = 0; j < 8; ++j) wbuf[j] = wsrc[j];
    }

    // ---- (3) wn -> LDS; barrier drains DMA + publishes wn ----
    {
        uint4* dst = (uint4*)(sw + srow * PITCH + shalf * 64);
        #pragma unroll
        for (int j = 0; j < 8; ++j) dst[j] = wbuf[j];
    }
    __syncthreads();

    // ---- (4) LDS -> A-frags + norm; MFMA; epilogue ----
    short8 af[4];
    float sc = convert_lds(pw, l15, quad, af);

    f32x4 acc[8];
    mfma_tile(sw, af, l15, quad, acc);

    float lsum = 0.0f;
    epilogue(acc, labv, sc, quad, l15, lsum);

    // ---- Wave + block reduction, one atomic per block ----
    #pragma unroll
    for (int m = 1; m < 64; m <<= 1) lsum += __shfl_xor(lsum, m, 64);
    if (lane == 0) swsum[wv] = lsum;
    __syncthreads();
    if (t == 0) {
        float tot = swsum[0] + swsum[1] + swsum[2] + swsum[3];
        atomicAdd(out, tot * (1.0f / (float)NB));
    }
}

extern "C" void kernel_launch(void* const* d_in, const int* in_sizes, int n_in,
                              void* d_out, int out_size, void* d_ws, size_t ws_size,
                              hipStream_t stream) {
    const float* predict = (const float*)d_in[0];
    const float* target  = (const float*)d_in[1];
    const float* weight  = (const float*)d_in[2];
    float* out = (float*)d_out;
    unsigned int* wn = (unsigned int*)d_ws;                   // 32 KB bf16 wn
    unsigned char* labs = (unsigned char*)d_ws + 32768;       // 128 KB labels

    wnorm_kernel<<<dim3(NC), dim3(64), 0, stream>>>(weight, wn, out);
    label_kernel<<<dim3(NB / 128), dim3(256), 0, stream>>>(target, labs);
    arcloss_kernel<<<dim3(NB / 64), dim3(256), 0, stream>>>(predict, labs,
                                                            (const unsigned short*)wn, out);
}

// Round 10
// 160.280 us; speedup vs baseline: 1.0189x; 1.0189x over previous
//
#include <hip/hip_runtime.h>
#include <hip/hip_bf16.h>
#include <math.h>

// Problem constants
#define NB 131072
#define NC 128
#define NE 128
__device__ constexpr float S_    = 100.0f;
__device__ constexpr float COSM_ = 0.5403023058681398f;   // cos(1)
__device__ constexpr float SINM_ = 0.8414709848078965f;   // sin(1)
__device__ constexpr float TH_   = -0.5403023058681398f;  // cos(pi-1)
__device__ constexpr float MM_   = 0.8414709848078965f;   // sin(pi-1)*1
__device__ constexpr float C0_   = 25.0f;                 // fixed logsumexp stabilizer

using short8 = __attribute__((ext_vector_type(8))) short;
using f32x4  = __attribute__((ext_vector_type(4))) float;

// packed fp32x2 -> bf16x2 (v_cvt_pk_bf16_f32)
__device__ __forceinline__ unsigned int pk2(float a, float b) {
    __hip_bfloat162 h = __float22bfloat162_rn(make_float2(a, b));
    union { __hip_bfloat162 h; unsigned int u; } cv; cv.h = h; return cv.u;
}
// fp32 -> bf16 (RNE) on raw bits (kernel 1)
__device__ __forceinline__ unsigned int bf1(float f) {
    unsigned int u = __float_as_uint(f);
    return (u + 0x7FFFu + ((u >> 16) & 1u)) >> 16;
}

// Kernel 1: normalize weight rows -> bf16 packed in ws; zero d_out.
__global__ void wnorm_kernel(const float* __restrict__ w,
                             unsigned int* __restrict__ wn,
                             float* __restrict__ out) {
    const int row = blockIdx.x;      // 128 rows
    const int lane = threadIdx.x;    // 64 lanes
    float2 v = ((const float2*)w)[row * 64 + lane];
    float ss = v.x * v.x + v.y * v.y;
    #pragma unroll
    for (int m = 1; m < 64; m <<= 1) ss += __shfl_xor(ss, m, 64);
    float sc = 1.0f / fmaxf(sqrtf(ss), 1e-12f);
    wn[row * 64 + lane] = bf1(v.x * sc) | (bf1(v.y * sc) << 16);
    if (row == 0 && lane == 0) *out = 0.0f;
}

constexpr int PITCH = 136;  // ushorts per LDS row for wn (272 B) — proven pattern

// global -> LDS DMA, 16 B per lane, fire-and-forget (counted by vmcnt).
__device__ __forceinline__ void gl2lds16(const void* g, void* l) {
    __builtin_amdgcn_global_load_lds(
        (const __attribute__((address_space(1))) void*)g,
        (__attribute__((address_space(3))) void*)l, 16, 0, 0);
}

// Stage one wave's 16-row predict slab (8 KB) into its private LDS buffer.
// 1 KB contiguous per instruction (rows 2j,2j+1); source carries the inverse
// XOR swizzle so the linear DMA dest lands pre-swizzled (rule #21).
__device__ __forceinline__ void stage_tile(const float* __restrict__ predict,
                                           long rowBase, float* lbase, int lane) {
    const char* g0 = (const char*)predict + rowBase * 512;
    const int rl_half = lane >> 5;
    const unsigned c = (unsigned)((lane & 31) * 16);
    #pragma unroll
    for (int j = 0; j < 8; ++j) {
        const int row_local = 2 * j + rl_half;
        const char* g = g0 + row_local * 512 + (c ^ ((unsigned)(row_local & 7) << 4));
        gl2lds16(g, (char*)lbase + j * 1024);
    }
}

// Read MFMA A-fragments (fp32, swizzled) from the wave's LDS slab,
// convert to bf16 + sumsq -> 1/||row|| (norm deferred to epilogue).
__device__ __forceinline__ float convert_lds(const float* pw, int l15, int quad,
                                             short8* af) {
    const char* base = (const char*)pw + l15 * 512;
    const unsigned swz = (unsigned)((l15 & 7) << 4);
    float s0 = 0.f;
    #pragma unroll
    for (int kc = 0; kc < 4; ++kc) {
        const unsigned b = (unsigned)(kc * 128 + quad * 32);
        float4 p0 = *(const float4*)(base + ((b) ^ swz));
        float4 p1 = *(const float4*)(base + ((b + 16) ^ swz));
        s0 += p0.x * p0.x + p0.y * p0.y + p0.z * p0.z + p0.w * p0.w;
        s0 += p1.x * p1.x + p1.y * p1.y + p1.z * p1.z + p1.w * p1.w;
        union { short8 s8; unsigned int u[4]; } uu;
        uu.u[0] = pk2(p0.x, p0.y);
        uu.u[1] = pk2(p0.z, p0.w);
        uu.u[2] = pk2(p1.x, p1.y);
        uu.u[3] = pk2(p1.z, p1.w);
        af[kc] = uu.s8;
    }
    s0 += __shfl_xor(s0, 16, 64);
    s0 += __shfl_xor(s0, 32, 64);
    return 1.0f / fmaxf(sqrtf(s0), 1e-12f);
}

__device__ __forceinline__ void mfma_tile(const unsigned short* sw, const short8* af,
                                          int l15, int quad, f32x4* acc) {
    #pragma unroll
    for (int tc = 0; tc < 8; ++tc) acc[tc] = (f32x4){0.f, 0.f, 0.f, 0.f};
    #pragma unroll 2
    for (int tc = 0; tc < 8; ++tc) {
        short8 b[4];
        #pragma unroll
        for (int kc = 0; kc < 4; ++kc)
            b[kc] = *(const short8*)(sw + (tc * 16 + l15) * PITCH + kc * 32 + quad * 8);
        #pragma unroll
        for (int kc = 0; kc < 4; ++kc)
            acc[tc] = __builtin_amdgcn_mfma_f32_16x16x32_bf16(af[kc], b[kc], acc[tc], 0, 0, 0);
    }
}

// arc-margin + per-row logsumexp contribution (R6-proven lean form)
__device__ __forceinline__ void epilogue(const f32x4* acc, int lab_all, float sc,
                                         int quad, int l15, float& lsum) {
    float se[4];
    #pragma unroll
    for (int v = 0; v < 4; ++v) {
        const int rl  = quad * 4 + v;
        const int lab = __shfl(lab_all, rl, 64);
        const float scv = __shfl(sc, rl, 64);
        const bool own  = (l15 == (lab & 15));
        const int  tcl  = lab >> 4;
        const float k1  = S_ * scv;
        float s = 1e-38f, craw = 0.f;
        #pragma unroll
        for (int tc = 0; tc < 8; ++tc) {
            float av = acc[tc][v];
            const bool isl = own && (tc == tcl);
            s += isl ? 0.f : __expf(fmaf(k1, av, -C0_));
            craw = isl ? av : craw;
        }
        float cl = craw * scv;
        float s2 = fmaxf(1.0f - cl * cl, 0.0f);
        float ph = cl * COSM_ - sqrtf(s2) * SINM_;
        ph = (cl > TH_) ? ph : (cl - MM_);
        s += own ? __expf(fmaf(S_, ph, -C0_)) : 0.f;
        lsum -= own ? S_ * ph : 0.f;
        se[v] = s;
    }
    #pragma unroll
    for (int m = 1; m < 16; m <<= 1) {
        #pragma unroll
        for (int v = 0; v < 4; ++v) se[v] += __shfl_xor(se[v], m, 64);
    }
    if (l15 == 0) {
        #pragma unroll
        for (int v = 0; v < 4; ++v) lsum += __logf(se[v]) + C0_;
    }
}

// Kernel 2: fused cosine GEMM + arc-margin + NLL + in-kernel labels.
// R15 = R14's one-shot DMA structure (42us, best measured) + R13's
// contiguous target loads fused in. Label VALU + target loads of block A
// overlap block B's DMA/compute via 8 block generations (the mechanism the
// standalone label kernel used to hit 5.3 TB/s). Kills the serial 12us
// label kernel, its launch, and the labs round-trip. Two launches total.
__global__ __launch_bounds__(256, 2)
void arcloss_kernel(const float* __restrict__ predict,
                    const float* __restrict__ target,
                    const unsigned short* __restrict__ wns,
                    float* __restrict__ out) {
    __shared__ __align__(16) unsigned short sw[128 * PITCH];  // 34816 B
    __shared__ __align__(16) float pbuf[4 * 2048];            // 4 waves x 8 KB
    __shared__ unsigned char labbuf[64];                      // 16 B per wave
    __shared__ float swsum[4];

    const int t    = threadIdx.x;
    const int lane = t & 63;
    const int wv   = t >> 6;         // 0..3
    const int l15  = lane & 15;
    const int quad = lane >> 4;
    const int l31  = lane & 31;
    const int half = lane >> 5;
    const long rowBase = (long)blockIdx.x * 64 + wv * 16;  // this wave's 16 rows
    float* pw = pbuf + wv * 2048;    // this wave's private slab

    // ---- (1) predict DMA first (no dest regs, fire-and-forget) ----
    stage_tile(predict, rowBase, pw, lane);

    // ---- (2) target: 16 rows contiguous, 1 KB/instruction, to regs ----
    float4 tv[8];
    {
        const char* src = (const char*)target + rowBase * 512;
        #pragma unroll
        for (int j = 0; j < 8; ++j)
            tv[j] = *(const float4*)(src + j * 1024 + lane * 16);
    }

    // ---- (3) wn loads (2 threads/row, 8 uint4 each) ----
    const int srow = t >> 1, shalf = t & 1;
    uint4 wbuf[8];
    {
        const uint4* wsrc = (const uint4*)(wns + srow * 128 + shalf * 64);
        #pragma unroll
        for (int j = 0; j < 8; ++j) wbuf[j] = wsrc[j];
    }

    // ---- (4) labels: iota-dot + 5-level shfl reduce per row pair (VALU,
    // runs as tv lands, under DMA latency). Lanes 0/32 -> wave's LDS slot. ----
    {
        const float c0 = (float)(l31 * 4);
        #pragma unroll
        for (int j = 0; j < 8; ++j) {
            float4 v = tv[j];
            float p = fmaf(v.x, c0, fmaf(v.y, c0 + 1.f,
                      fmaf(v.z, c0 + 2.f, v.w * (c0 + 3.f))));
            p += __shfl_xor(p, 1, 64);
            p += __shfl_xor(p, 2, 64);
            p += __shfl_xor(p, 4, 64);
            p += __shfl_xor(p, 8, 64);
            p += __shfl_xor(p, 16, 64);
            if (l31 == 0) labbuf[wv * 16 + 2 * j + half] = (unsigned char)(int)(p + 0.5f);
        }
    }

    // ---- (5) wn -> LDS; barrier drains DMA + publishes wn ----
    {
        uint4* dst = (uint4*)(sw + srow * PITCH + shalf * 64);
        #pragma unroll
        for (int j = 0; j < 8; ++j) dst[j] = wbuf[j];
    }
    __syncthreads();

    // label for this lane's row (same-wave LDS slot, lgkm-ordered)
    const int labv = labbuf[wv * 16 + l15];

    // ---- (6) LDS -> A-frags + norm; MFMA; epilogue ----
    short8 af[4];
    float sc = convert_lds(pw, l15, quad, af);

    f32x4 acc[8];
    mfma_tile(sw, af, l15, quad, acc);

    float lsum = 0.0f;
    epilogue(acc, labv, sc, quad, l15, lsum);

    // ---- Wave + block reduction, one atomic per block ----
    #pragma unroll
    for (int m = 1; m < 64; m <<= 1) lsum += __shfl_xor(lsum, m, 64);
    if (lane == 0) swsum[wv] = lsum;
    __syncthreads();
    if (t == 0) {
        float tot = swsum[0] + swsum[1] + swsum[2] + swsum[3];
        atomicAdd(out, tot * (1.0f / (float)NB));
    }
}

extern "C" void kernel_launch(void* const* d_in, const int* in_sizes, int n_in,
                              void* d_out, int out_size, void* d_ws, size_t ws_size,
                              hipStream_t stream) {
    const float* predict = (const float*)d_in[0];
    const float* target  = (const float*)d_in[1];
    const float* weight  = (const float*)d_in[2];
    float* out = (float*)d_out;
    unsigned int* wn = (unsigned int*)d_ws;  // 128*64 uints = 32 KB bf16 wn

    wnorm_kernel<<<dim3(NC), dim3(64), 0, stream>>>(weight, wn, out);
    arcloss_kernel<<<dim3(NB / 64), dim3(256), 0, stream>>>(predict, target,
                                                            (const unsigned short*)wn, out);
}

// Round 11
// 152.186 us; speedup vs baseline: 1.0731x; 1.0532x over previous
//
#include <hip/hip_runtime.h>
#include <hip/hip_bf16.h>
#include <math.h>

// Problem constants
#define NB 131072
#define NC 128
#define NE 128
__device__ constexpr float S_    = 100.0f;
__device__ constexpr float COSM_ = 0.5403023058681398f;   // cos(1)
__device__ constexpr float SINM_ = 0.8414709848078965f;   // sin(1)
__device__ constexpr float TH_   = -0.5403023058681398f;  // cos(pi-1)
__device__ constexpr float MM_   = 0.8414709848078965f;   // sin(pi-1)*1
__device__ constexpr float C0_   = 25.0f;                 // fixed logsumexp stabilizer

using short8 = __attribute__((ext_vector_type(8))) short;
using f32x4  = __attribute__((ext_vector_type(4))) float;

// fp32 -> bf16 (RNE) on raw bits (kernel 1)
__device__ __forceinline__ unsigned int bf1(float f) {
    unsigned int u = __float_as_uint(f);
    return (u + 0x7FFFu + ((u >> 16) & 1u)) >> 16;
}
// packed fp32x2 -> bf16x2 (v_cvt_pk_bf16_f32)
__device__ __forceinline__ unsigned int pk2(float a, float b) {
    __hip_bfloat162 h = __float22bfloat162_rn(make_float2(a, b));
    union { __hip_bfloat162 h; unsigned int u; } cv; cv.h = h; return cv.u;
}

// Kernel 1: normalize weight rows -> bf16 packed in ws; zero d_out.
__global__ void wnorm_kernel(const float* __restrict__ w,
                             unsigned int* __restrict__ wn,
                             float* __restrict__ out) {
    const int row = blockIdx.x;      // 128 rows
    const int lane = threadIdx.x;    // 64 lanes
    float2 v = ((const float2*)w)[row * 64 + lane];
    float ss = v.x * v.x + v.y * v.y;
    #pragma unroll
    for (int m = 1; m < 64; m <<= 1) ss += __shfl_xor(ss, m, 64);
    float sc = 1.0f / fmaxf(sqrtf(ss), 1e-12f);
    wn[row * 64 + lane] = bf1(v.x * sc) | (bf1(v.y * sc) << 16);
    if (row == 0 && lane == 0) *out = 0.0f;
}

// Kernel 2: fused cosine GEMM + arc-margin + NLL.
// R16 = R8 (best bench, 149.9) restored, with __launch_bounds__(512,4):
// final occupancy probe — 4 blocks/CU x 8 waves = 32 waves/CU (cap 64 VGPR
// vs 44 measured at R8, so no spill expected; LDS 4x35.3=141KB fits).
// Ledger across R6..R15: GEMM-part ~42us + target ~10-15us + wnorm ~2us is
// conserved under every structure (one-shot/persistent, strided/DMA,
// split/fused, 8..24 waves/CU). If this is flat too, occupancy is fully
// falsified as the lever and the remaining 2.5x-to-roofline gap is the
// per-block load->barrier->compute phase serialization the compiler
// re-creates at HIP source level (needs an inline-asm interleaved loop).
__global__ __launch_bounds__(512, 4)
void arcloss_kernel(const float* __restrict__ predict,
                    const float* __restrict__ target,
                    const unsigned short* __restrict__ wns,
                    float* __restrict__ out) {
    constexpr int PITCH = 136;  // ushorts per LDS row (272 B) — breaks pow2 bank stride
    __shared__ __align__(16) unsigned short sw[128 * PITCH];
    __shared__ float swsum[8];

    const int t    = threadIdx.x;
    const int lane = t & 63;
    const int wv   = t >> 6;         // 0..7
    const int l15  = lane & 15;
    const int quad = lane >> 4;
    const long rowbase = (long)blockIdx.x * 128 + wv * 16;  // this wave's 16 rows

    // ---- (1) Issue wn staging loads FIRST (4 threads/row, 4 uint4 each) ----
    const int srow = t >> 2, sq = t & 3;
    uint4 wbuf[4];
    {
        const uint4* wsrc = (const uint4*)(wns + srow * 128 + sq * 32);
        #pragma unroll
        for (int j = 0; j < 4; ++j) wbuf[j] = wsrc[j];
    }

    // ---- (2) Issue predict loads (8 float4 per lane) ----
    float4 praw0[8];
    {
        const float* prow = predict + (rowbase + l15) * NE + quad * 8;
        #pragma unroll
        for (int kc = 0; kc < 4; ++kc) {
            praw0[kc * 2]     = *(const float4*)(prow + kc * 32);
            praw0[kc * 2 + 1] = *(const float4*)(prow + kc * 32 + 4);
        }
    }

    // ---- (3) Labels: 4 lanes per row, each scans 32 cols, rolling consume ----
    int lab_all;
    {
        const int r = lane & 15, q = lane >> 4;
        const float4* trow = (const float4*)(target + (rowbase + r) * NC + q * 32);
        float a0 = 0.f, a1 = 0.f;
        #pragma unroll
        for (int i = 0; i < 8; i += 2) {
            float4 t0 = trow[i];
            float4 t1 = trow[i + 1];
            float c0 = (float)(q * 32 + i * 4);
            a0 = fmaf(t0.x, c0,       a0); a0 = fmaf(t0.y, c0 + 1.f, a0);
            a0 = fmaf(t0.z, c0 + 2.f, a0); a0 = fmaf(t0.w, c0 + 3.f, a0);
            a1 = fmaf(t1.x, c0 + 4.f, a1); a1 = fmaf(t1.y, c0 + 5.f, a1);
            a1 = fmaf(t1.z, c0 + 6.f, a1); a1 = fmaf(t1.w, c0 + 7.f, a1);
        }
        float lf = a0 + a1;
        lf += __shfl_xor(lf, 16, 64);
        lf += __shfl_xor(lf, 32, 64);
        lab_all = (int)(lf + 0.5f);     // lane L holds label of row (L&15)
    }

    // ---- (4) wn -> LDS, single barrier ----
    {
        uint4* dst = (uint4*)(sw + srow * PITCH + sq * 32);
        #pragma unroll
        for (int j = 0; j < 4; ++j) dst[j] = wbuf[j];
    }
    __syncthreads();

    // ---- convert to A-frags + sumsq (norm deferred) ----
    short8 af0[4];
    float sc0;
    {
        float s0 = 0.f;
        #pragma unroll
        for (int kc = 0; kc < 4; ++kc) {
            float4 p0 = praw0[kc * 2], p1 = praw0[kc * 2 + 1];
            s0 += p0.x * p0.x + p0.y * p0.y + p0.z * p0.z + p0.w * p0.w;
            s0 += p1.x * p1.x + p1.y * p1.y + p1.z * p1.z + p1.w * p1.w;
            union { short8 s8; unsigned int u[4]; } uu;
            uu.u[0] = pk2(p0.x, p0.y);
            uu.u[1] = pk2(p0.z, p0.w);
            uu.u[2] = pk2(p1.x, p1.y);
            uu.u[3] = pk2(p1.z, p1.w);
            af0[kc] = uu.s8;
        }
        s0 += __shfl_xor(s0, 16, 64);
        s0 += __shfl_xor(s0, 32, 64);
        sc0 = 1.0f / fmaxf(sqrtf(s0), 1e-12f);
    }

    float lsum = 0.0f;

    // ---- MFMA: 8 class-column tiles x 4 K-chunks ----
    f32x4 acc[8];
    #pragma unroll
    for (int tc = 0; tc < 8; ++tc) acc[tc] = (f32x4){0.f, 0.f, 0.f, 0.f};
    #pragma unroll 2
    for (int tc = 0; tc < 8; ++tc) {
        short8 b[4];
        #pragma unroll
        for (int kc = 0; kc < 4; ++kc)
            b[kc] = *(const short8*)(sw + (tc * 16 + l15) * PITCH + kc * 32 + quad * 8);
        #pragma unroll
        for (int kc = 0; kc < 4; ++kc)
            acc[tc] = __builtin_amdgcn_mfma_f32_16x16x32_bf16(af0[kc], b[kc], acc[tc], 0, 0, 0);
    }

    // ---- epilogue (R6-proven lean form) ----
    {
        float se[4];
        #pragma unroll
        for (int v = 0; v < 4; ++v) {
            const int rl  = quad * 4 + v;
            const int lab = __shfl(lab_all, rl, 64);
            const float scv = __shfl(sc0, rl, 64);
            const bool own  = (l15 == (lab & 15));
            const int  tcl  = lab >> 4;
            const float k1  = S_ * scv;
            float s = 1e-38f, craw = 0.f;
            #pragma unroll
            for (int tc = 0; tc < 8; ++tc) {
                float av = acc[tc][v];
                const bool isl = own && (tc == tcl);
                s += isl ? 0.f : __expf(fmaf(k1, av, -C0_));
                craw = isl ? av : craw;
            }
            float cl = craw * scv;
            float s2 = fmaxf(1.0f - cl * cl, 0.0f);
            float ph = cl * COSM_ - sqrtf(s2) * SINM_;
            ph = (cl > TH_) ? ph : (cl - MM_);
            s += own ? __expf(fmaf(S_, ph, -C0_)) : 0.f;
            lsum -= own ? S_ * ph : 0.f;
            se[v] = s;
        }
        #pragma unroll
        for (int m = 1; m < 16; m <<= 1) {
            #pragma unroll
            for (int v = 0; v < 4; ++v) se[v] += __shfl_xor(se[v], m, 64);
        }
        if (l15 == 0) {
            #pragma unroll
            for (int v = 0; v < 4; ++v) lsum += __logf(se[v]) + C0_;
        }
    }

    // ---- Wave + block reduction, one atomic per block ----
    #pragma unroll
    for (int m = 1; m < 64; m <<= 1) lsum += __shfl_xor(lsum, m, 64);
    if (lane == 0) swsum[wv] = lsum;
    __syncthreads();
    if (t == 0) {
        float tot = 0.f;
        #pragma unroll
        for (int w = 0; w < 8; ++w) tot += swsum[w];
        atomicAdd(out, tot * (1.0f / (float)NB));
    }
}

extern "C" void kernel_launch(void* const* d_in, const int* in_sizes, int n_in,
                              void* d_out, int out_size, void* d_ws, size_t ws_size,
                              hipStream_t stream) {
    const float* predict = (const float*)d_in[0];
    const float* target  = (const float*)d_in[1];
    const float* weight  = (const float*)d_in[2];
    float* out = (float*)d_out;
    unsigned int* wn = (unsigned int*)d_ws;  // 128*64 uints = 32 KB bf16 wn

    wnorm_kernel<<<dim3(NC), dim3(64), 0, stream>>>(weight, wn, out);
    arcloss_kernel<<<dim3(NB / 128), dim3(512), 0, stream>>>(predict, target,
                                                             (const unsigned short*)wn, out);
}